// Round 4
// baseline (622.930 us; speedup 1.0000x reference)
//
#include <hip/hip_runtime.h>
#include <hip/hip_bf16.h>

#define NQ     14
#define DIM    16384
#define NLAYER 16
#define BATCH  512
#define NT     1024

// bijective LDS swizzle: XOR bits 5..9 into bits 0..4 (bank-conflict killer)
__device__ __forceinline__ int POS(int x){ return x ^ ((x >> 5) & 31); }

__device__ __forceinline__ float bf2f(unsigned int u16){
  union { unsigned int i; float f; } v; v.i = u16 << 16; return v.f;
}

// theta accessor: harness may deliver float inputs as bf16; branch on sniffed flag
__device__ __forceinline__ float thv(const void* th, int i, bool b16){
  return b16 ? bf2f(((const unsigned short*)th)[i]) : ((const float*)th)[i];
}

// Composed CNOT-ring source map: psi_out[x] = psi_in[srcF(x)].
// cnot(k, (k+1)%14): control qubit k = index bit (13-k), target bit 13-((k+1)%14).
// Applied w=0..13 in order -> src = m0(m1(...m13(x))); linear over GF(2).
__device__ int srcF(int x){
  int v = x;
  #pragma unroll
  for (int k = 13; k >= 0; --k){
    int tb = 13 - ((k + 1) % 14);
    v ^= ((v >> (13 - k)) & 1) << tb;
  }
  return v;
}

__device__ __forceinline__ void rot2(float2& a0, float2& a1, float c, float s){
  float2 t0 = a0, t1 = a1;
  a0 = make_float2(c*t0.x - s*t1.x, c*t0.y - s*t1.y);
  a1 = make_float2(s*t0.x + c*t1.x, s*t0.y + c*t1.y);
}

__device__ __forceinline__ float2 cmulph(float2 a, float2 ch, float2 cl){
  // a * (ch.x + i ch.y) * (cl.x + i cl.y)
  float cc = ch.x*cl.x - ch.y*cl.y;
  float ss = ch.x*cl.y + ch.y*cl.x;
  return make_float2(a.x*cc - a.y*ss, a.x*ss + a.y*cc);
}

// 4 waves/EU (= 16 waves = one 1024-thread block per CU, LDS-forced anyway)
// -> VGPR cap 128/thread: a[16] float2 accumulator fits WITHOUT scratch spills.
// (launch_bounds(1024) alone capped VGPRs at 64 -> 825 MB/dispatch spill traffic.)
__global__ __launch_bounds__(NT, 4)
void qnn_circuit(const void* __restrict__ zraw,
                 const void* __restrict__ theta,
                 float* __restrict__ out)
{
  __shared__ float2 S[DIM];                                   // 128 KiB state
  __shared__ float2 ph0H[128], ph0L[128], ph2H[128], ph2L[128]; // RZ cos/sin
  __shared__ float  csT[28];                                  // RY cos/sin
  __shared__ int    srcH[128], srcL[128];                     // CNOT perm tables
  __shared__ float  red[16*5];

  const int t = threadIdx.x;
  const int b = blockIdx.x;

  // ---- sniff theta dtype: bf16 vs float32 ----
  int pred = 0;
  if (t < 336){
    unsigned int w  = ((const unsigned int*)theta)[t];  // 1344 B, in-bounds either way
    unsigned int lo = w & 0xffffu;
    unsigned int e  = (lo >> 7) & 0xffu;
    pred = (e >= 100 && e <= 140) || (lo == 0);
  }
  const bool th_b16 = (__syncthreads_count(pred) > 250);

  // ---- sniff z format: bf16 (re,im) pairs  vs  float32 real-part-only ----
  pred = 0;
  if (t < 256){
    unsigned int w  = ((const unsigned int*)zraw)[t];
    unsigned int lo = w & 0xffffu;
    unsigned int e  = (lo >> 7) & 0xffu;
    pred = (e >= 88 && e <= 140) || (lo == 0);
  }
  const bool z_b16 = (__syncthreads_count(pred) > 160);

  if (t < 128){ srcH[t] = srcF(t << 7); srcL[t] = srcF(t); }

  // ---- load z -> LDS (swizzled), per sniffed format ----
  if (z_b16){
    const uint4* zb = (const uint4*)((const unsigned short*)zraw + (size_t)b * (DIM * 2));
    #pragma unroll
    for (int jj = 0; jj < 4; ++jj){
      int x4 = t + NT * jj;
      uint4 w = zb[x4];
      int xb = x4 * 4;
      S[POS(xb+0)] = make_float2(bf2f(w.x & 0xffffu), bf2f(w.x >> 16));
      S[POS(xb+1)] = make_float2(bf2f(w.y & 0xffffu), bf2f(w.y >> 16));
      S[POS(xb+2)] = make_float2(bf2f(w.z & 0xffffu), bf2f(w.z >> 16));
      S[POS(xb+3)] = make_float2(bf2f(w.w & 0xffffu), bf2f(w.w >> 16));
    }
  } else {
    const float4* zf = (const float4*)((const float*)zraw + (size_t)b * DIM);
    #pragma unroll
    for (int jj = 0; jj < 4; ++jj){
      int x4 = t + NT * jj;
      float4 w = zf[x4];
      int xb = x4 * 4;
      S[POS(xb+0)] = make_float2(w.x, 0.f);
      S[POS(xb+1)] = make_float2(w.y, 0.f);
      S[POS(xb+2)] = make_float2(w.z, 0.f);
      S[POS(xb+3)] = make_float2(w.w, 0.f);
    }
  }
  __syncthreads();

  float2 a[16];

  for (int l = 0; l < NLAYER; ++l){
    const int thb = l * 42;

    // ---- prep: RZ phase tables (H = qubits 0..6 <-> x[13:7], L = 7..13) + RY angles
    if (t < 512){
      int grp = t >> 7, idx = t & 127;
      int tz = thb + ((grp >= 2) ? 28 : 0);
      float ph = 0.f;
      if ((grp & 1) == 0){
        #pragma unroll
        for (int w = 0; w < 7; ++w)
          ph += (((idx >> (6 - w)) & 1) ? 0.5f : -0.5f) * thv(theta, tz + w, th_b16);
      } else {
        #pragma unroll
        for (int w = 7; w < 14; ++w)
          ph += (((idx >> (13 - w)) & 1) ? 0.5f : -0.5f) * thv(theta, tz + w, th_b16);
      }
      float sn, cs; sincosf(ph, &sn, &cs);
      float2 v = make_float2(cs, sn);
      if      (grp == 0) ph0H[idx] = v;
      else if (grp == 1) ph0L[idx] = v;
      else if (grp == 2) ph2H[idx] = v;
      else               ph2L[idx] = v;
    } else if (t < 512 + 14){
      int q = t - 512;
      float sn, cs; sincosf(0.5f * thv(theta, thb + 14 + q, th_b16), &sn, &cs);
      csT[2*q] = cs; csT[2*q+1] = sn;
    }

    // ---- P1: gather (undo previous CNOT ring) + RZ0 + RY qubits 0..3 ----
    // thread t holds x = t + 1024*j  (j = x bits 13..10)
    if (l == 0){
      #pragma unroll
      for (int j = 0; j < 16; ++j) a[j] = S[POS(t + NT*j)];
    } else {
      int sl = srcL[t & 127];
      #pragma unroll
      for (int j = 0; j < 16; ++j)
        a[j] = S[POS(srcH[(t >> 7) + 8*j] ^ sl)];
    }
    __syncthreads();   // gathers done; tables visible

    {
      float2 cl = ph0L[t & 127];
      #pragma unroll
      for (int j = 0; j < 16; ++j)
        a[j] = cmulph(a[j], ph0H[(t >> 7) + 8*j], cl);
    }
    #pragma unroll
    for (int q = 0; q < 4; ++q){
      float c = csT[2*q], s = csT[2*q+1];
      int m = 8 >> q;
      #pragma unroll
      for (int j = 0; j < 16; ++j){
        if (j & m) continue;
        rot2(a[j], a[j | m], c, s);
      }
    }
    #pragma unroll
    for (int j = 0; j < 16; ++j) S[POS(t + NT*j)] = a[j];
    __syncthreads();

    // ---- P2: RY qubits 4..7 (x bits 9..6) ----
    {
      int base = ((t >> 6) << 10) | (t & 63);
      #pragma unroll
      for (int j = 0; j < 16; ++j) a[j] = S[POS(base | (j << 6))];
      #pragma unroll
      for (int q = 0; q < 4; ++q){
        float c = csT[2*(4+q)], s = csT[2*(4+q)+1];
        int m = 8 >> q;
        #pragma unroll
        for (int j = 0; j < 16; ++j){
          if (j & m) continue;
          rot2(a[j], a[j | m], c, s);
        }
      }
      #pragma unroll
      for (int j = 0; j < 16; ++j) S[POS(base | (j << 6))] = a[j];
    }
    __syncthreads();

    // ---- P3: RY qubits 8..10 (x bits 5..3) ----
    #pragma unroll
    for (int it = 0; it < 2; ++it){
      int s4 = t + NT * it;
      int base = (s4 & 7) | (((s4 >> 3) & 7) << 8) | (((s4 >> 6) & 3) << 6)
               | (((s4 >> 8) & 7) << 11);
      #pragma unroll
      for (int j = 0; j < 8; ++j) a[j] = S[POS(base | (j << 3))];
      #pragma unroll
      for (int q = 0; q < 3; ++q){
        float c = csT[2*(8+q)], s = csT[2*(8+q)+1];
        int m = 4 >> q;
        #pragma unroll
        for (int j = 0; j < 8; ++j){
          if (j & m) continue;
          rot2(a[j], a[j | m], c, s);
        }
      }
      #pragma unroll
      for (int j = 0; j < 8; ++j) S[POS(base | (j << 3))] = a[j];
    }
    __syncthreads();

    // ---- P4: RY qubits 11..13 (x bits 2..0) + RZ2 ----
    #pragma unroll
    for (int it = 0; it < 2; ++it){
      int s4 = t + NT * it;
      int base = ((s4 & 63) << 5) | (((s4 >> 6) & 3) << 3) | (((s4 >> 8) & 7) << 11);
      #pragma unroll
      for (int j = 0; j < 8; ++j) a[j] = S[POS(base | j)];
      #pragma unroll
      for (int q = 0; q < 3; ++q){
        float c = csT[2*(11+q)], s = csT[2*(11+q)+1];
        int m = 4 >> q;
        #pragma unroll
        for (int j = 0; j < 8; ++j){
          if (j & m) continue;
          rot2(a[j], a[j | m], c, s);
        }
      }
      #pragma unroll
      for (int j = 0; j < 8; ++j){
        int x = base | j;
        a[j] = cmulph(a[j], ph2H[x >> 7], ph2L[x & 127]);
      }
      #pragma unroll
      for (int j = 0; j < 8; ++j) S[POS(base | j)] = a[j];
    }
    __syncthreads();
  }

  // ---- measurement (final CNOT ring still pending -> gather via src) ----
  float z0=0.f, z1=0.f, x0s=0.f, x1s=0.f, y0s=0.f;
  {
    int sl = srcL[t & 127];
    #pragma unroll
    for (int j = 0; j < 16; ++j)
      a[j] = S[POS(srcH[(t >> 7) + 8*j] ^ sl)];

    #pragma unroll
    for (int j = 0; j < 16; ++j){
      float pw = a[j].x*a[j].x + a[j].y*a[j].y;
      z0 += (j & 8) ? -pw : pw;     // qubit0 = x bit13 = j bit3
      z1 += (j & 4) ? -pw : pw;     // qubit1 = x bit12 = j bit2
    }
    #pragma unroll
    for (int j = 0; j < 8; ++j){
      float2 p0 = a[j], p1 = a[j+8];
      x0s += 2.f*(p0.x*p1.x + p0.y*p1.y);
      y0s += 2.f*(p0.x*p1.y - p0.y*p1.x);
    }
    #pragma unroll
    for (int j = 0; j < 16; ++j){
      if (j & 4) continue;
      float2 p0 = a[j], p1 = a[j|4];
      x1s += 2.f*(p0.x*p1.x + p0.y*p1.y);
    }
  }
  #pragma unroll
  for (int o = 32; o >= 1; o >>= 1){
    z0  += __shfl_down(z0,  o, 64);
    z1  += __shfl_down(z1,  o, 64);
    x0s += __shfl_down(x0s, o, 64);
    x1s += __shfl_down(x1s, o, 64);
    y0s += __shfl_down(y0s, o, 64);
  }
  int wid = t >> 6, lane = t & 63;
  if (lane == 0){
    red[wid*5+0]=z0; red[wid*5+1]=z1; red[wid*5+2]=x0s; red[wid*5+3]=x1s; red[wid*5+4]=y0s;
  }
  __syncthreads();
  if (t < 5){
    float sum = 0.f;
    #pragma unroll
    for (int w = 0; w < 16; ++w) sum += red[w*5 + t];
    out[1 + b*5 + t] = sum;
  }
}

__global__ __launch_bounds__(512)
void qnn_loss(const int* __restrict__ y, float* __restrict__ out)
{
  __shared__ float red[8];
  int t = threadIdx.x;   // one thread per batch element
  const float* o = out + 1 + t*5;
  float o0=o[0], o1=o[1], o2=o[2], o3=o[3], o4=o[4];
  float m = fmaxf(fmaxf(fmaxf(o0,o1), fmaxf(o2,o3)), o4);
  float sum = expf(o0-m)+expf(o1-m)+expf(o2-m)+expf(o3-m)+expf(o4-m);
  float lse = m + logf(sum);
  int yi = y[t]; yi = yi < 0 ? 0 : (yi > 4 ? 4 : yi);
  float lb = lse - o[yi];

  #pragma unroll
  for (int ofs = 32; ofs >= 1; ofs >>= 1) lb += __shfl_down(lb, ofs, 64);
  if ((t & 63) == 0) red[t >> 6] = lb;
  __syncthreads();
  if (t == 0){
    float s = 0.f;
    #pragma unroll
    for (int w = 0; w < 8; ++w) s += red[w];
    out[0] = s / (float)BATCH;
  }
}

extern "C" void kernel_launch(void* const* d_in, const int* in_sizes, int n_in,
                              void* d_out, int out_size, void* d_ws, size_t ws_size,
                              hipStream_t stream)
{
  const void* z     = d_in[0];            // bf16 (re,im) pairs OR f32 real (sniffed)
  const void* theta = d_in[1];            // bf16 or f32 (sniffed)
  const int*  y     = (const int*)d_in[2];
  float*      out   = (float*)d_out;

  qnn_circuit<<<BATCH, NT, 0, stream>>>(z, theta, out);
  qnn_loss<<<1, 512, 0, stream>>>(y, out);
}

// Round 5
// 622.767 us; speedup vs baseline: 1.0003x; 1.0003x over previous
//
#include <hip/hip_runtime.h>
#include <hip/hip_bf16.h>

#define NQ     14
#define DIM    16384
#define NLAYER 16
#define BATCH  512
#define NT     1024

// bijective LDS swizzle: XOR bits 5..9 into bits 0..4 (bank-conflict killer)
__device__ __forceinline__ int POS(int x){ return x ^ ((x >> 5) & 31); }

__device__ __forceinline__ float bf2f(unsigned int u16){
  union { unsigned int i; float f; } v; v.i = u16 << 16; return v.f;
}

// theta accessor: harness may deliver float inputs as bf16; branch on sniffed flag
__device__ __forceinline__ float thv(const void* th, int i, bool b16){
  return b16 ? bf2f(((const unsigned short*)th)[i]) : ((const float*)th)[i];
}

// Composed CNOT-ring source map: psi_out[x] = psi_in[srcF(x)].
// cnot(k, (k+1)%14): control qubit k = index bit (13-k), target bit 13-((k+1)%14).
// Applied w=0..13 in order -> src = m0(m1(...m13(x))); linear over GF(2).
__device__ int srcF(int x){
  int v = x;
  #pragma unroll
  for (int k = 13; k >= 0; --k){
    int tb = 13 - ((k + 1) % 14);
    v ^= ((v >> (13 - k)) & 1) << tb;
  }
  return v;
}

__device__ __forceinline__ void rot2(float2& a0, float2& a1, float c, float s){
  float2 t0 = a0, t1 = a1;
  a0 = make_float2(c*t0.x - s*t1.x, c*t0.y - s*t1.y);
  a1 = make_float2(s*t0.x + c*t1.x, s*t0.y + c*t1.y);
}

__device__ __forceinline__ float2 cmulph(float2 a, float2 ch, float2 cl){
  // a * (ch.x + i ch.y) * (cl.x + i cl.y)
  float cc = ch.x*cl.x - ch.y*cl.y;
  float ss = ch.x*cl.y + ch.y*cl.x;
  return make_float2(a.x*cc - a.y*ss, a.x*ss + a.y*cc);
}

// LDS (134 KiB) forces 1 block/CU = 16 waves = 4 waves/EU. Pin the register
// allocator to EXACTLY that occupancy: waves_per_eu(4,4) -> 128-VGPR budget.
// (launch_bounds(NT,4) only sets the MIN; allocator still targeted 8 waves/EU
// -> 64 VGPRs -> 837 MB/dispatch scratch spill traffic, measured r3/r4.)
__global__ __launch_bounds__(NT) __attribute__((amdgpu_waves_per_eu(4, 4)))
void qnn_circuit(const void* __restrict__ zraw,
                 const void* __restrict__ theta,
                 float* __restrict__ out)
{
  __shared__ float2 S[DIM];                                   // 128 KiB state
  __shared__ float2 ph0H[128], ph0L[128], ph2H[128], ph2L[128]; // RZ cos/sin
  __shared__ float  csT[28];                                  // RY cos/sin
  __shared__ int    srcH[128], srcL[128];                     // CNOT perm tables
  __shared__ float  red[16*5];

  const int t = threadIdx.x;
  const int b = blockIdx.x;

  // ---- sniff theta dtype: bf16 vs float32 ----
  int pred = 0;
  if (t < 336){
    unsigned int w  = ((const unsigned int*)theta)[t];  // 1344 B, in-bounds either way
    unsigned int lo = w & 0xffffu;
    unsigned int e  = (lo >> 7) & 0xffu;
    pred = (e >= 100 && e <= 140) || (lo == 0);
  }
  const bool th_b16 = (__syncthreads_count(pred) > 250);

  // ---- sniff z format: bf16 (re,im) pairs  vs  float32 real-part-only ----
  pred = 0;
  if (t < 256){
    unsigned int w  = ((const unsigned int*)zraw)[t];
    unsigned int lo = w & 0xffffu;
    unsigned int e  = (lo >> 7) & 0xffu;
    pred = (e >= 88 && e <= 140) || (lo == 0);
  }
  const bool z_b16 = (__syncthreads_count(pred) > 160);

  if (t < 128){ srcH[t] = srcF(t << 7); srcL[t] = srcF(t); }

  // ---- load z -> LDS (swizzled), per sniffed format ----
  if (z_b16){
    const uint4* zb = (const uint4*)((const unsigned short*)zraw + (size_t)b * (DIM * 2));
    #pragma unroll
    for (int jj = 0; jj < 4; ++jj){
      int x4 = t + NT * jj;
      uint4 w = zb[x4];
      int xb = x4 * 4;
      S[POS(xb+0)] = make_float2(bf2f(w.x & 0xffffu), bf2f(w.x >> 16));
      S[POS(xb+1)] = make_float2(bf2f(w.y & 0xffffu), bf2f(w.y >> 16));
      S[POS(xb+2)] = make_float2(bf2f(w.z & 0xffffu), bf2f(w.z >> 16));
      S[POS(xb+3)] = make_float2(bf2f(w.w & 0xffffu), bf2f(w.w >> 16));
    }
  } else {
    const float4* zf = (const float4*)((const float*)zraw + (size_t)b * DIM);
    #pragma unroll
    for (int jj = 0; jj < 4; ++jj){
      int x4 = t + NT * jj;
      float4 w = zf[x4];
      int xb = x4 * 4;
      S[POS(xb+0)] = make_float2(w.x, 0.f);
      S[POS(xb+1)] = make_float2(w.y, 0.f);
      S[POS(xb+2)] = make_float2(w.z, 0.f);
      S[POS(xb+3)] = make_float2(w.w, 0.f);
    }
  }
  __syncthreads();

  float2 a[16];

  for (int l = 0; l < NLAYER; ++l){
    const int thb = l * 42;

    // ---- prep: RZ phase tables (H = qubits 0..6 <-> x[13:7], L = 7..13) + RY angles
    if (t < 512){
      int grp = t >> 7, idx = t & 127;
      int tz = thb + ((grp >= 2) ? 28 : 0);
      float ph = 0.f;
      if ((grp & 1) == 0){
        #pragma unroll
        for (int w = 0; w < 7; ++w)
          ph += (((idx >> (6 - w)) & 1) ? 0.5f : -0.5f) * thv(theta, tz + w, th_b16);
      } else {
        #pragma unroll
        for (int w = 7; w < 14; ++w)
          ph += (((idx >> (13 - w)) & 1) ? 0.5f : -0.5f) * thv(theta, tz + w, th_b16);
      }
      float sn, cs; sincosf(ph, &sn, &cs);
      float2 v = make_float2(cs, sn);
      if      (grp == 0) ph0H[idx] = v;
      else if (grp == 1) ph0L[idx] = v;
      else if (grp == 2) ph2H[idx] = v;
      else               ph2L[idx] = v;
    } else if (t < 512 + 14){
      int q = t - 512;
      float sn, cs; sincosf(0.5f * thv(theta, thb + 14 + q, th_b16), &sn, &cs);
      csT[2*q] = cs; csT[2*q+1] = sn;
    }

    // ---- P1: gather (undo previous CNOT ring) + RZ0 + RY qubits 0..3 ----
    // thread t holds x = t + 1024*j  (j = x bits 13..10)
    if (l == 0){
      #pragma unroll
      for (int j = 0; j < 16; ++j) a[j] = S[POS(t + NT*j)];
    } else {
      int sl = srcL[t & 127];
      #pragma unroll
      for (int j = 0; j < 16; ++j)
        a[j] = S[POS(srcH[(t >> 7) + 8*j] ^ sl)];
    }
    __syncthreads();   // gathers done; tables visible

    {
      float2 cl = ph0L[t & 127];
      #pragma unroll
      for (int j = 0; j < 16; ++j)
        a[j] = cmulph(a[j], ph0H[(t >> 7) + 8*j], cl);
    }
    #pragma unroll
    for (int q = 0; q < 4; ++q){
      float c = csT[2*q], s = csT[2*q+1];
      int m = 8 >> q;
      #pragma unroll
      for (int j = 0; j < 16; ++j){
        if (j & m) continue;
        rot2(a[j], a[j | m], c, s);
      }
    }
    #pragma unroll
    for (int j = 0; j < 16; ++j) S[POS(t + NT*j)] = a[j];
    __syncthreads();

    // ---- P2: RY qubits 4..7 (x bits 9..6) ----
    {
      int base = ((t >> 6) << 10) | (t & 63);
      #pragma unroll
      for (int j = 0; j < 16; ++j) a[j] = S[POS(base | (j << 6))];
      #pragma unroll
      for (int q = 0; q < 4; ++q){
        float c = csT[2*(4+q)], s = csT[2*(4+q)+1];
        int m = 8 >> q;
        #pragma unroll
        for (int j = 0; j < 16; ++j){
          if (j & m) continue;
          rot2(a[j], a[j | m], c, s);
        }
      }
      #pragma unroll
      for (int j = 0; j < 16; ++j) S[POS(base | (j << 6))] = a[j];
    }
    __syncthreads();

    // ---- P3: RY qubits 8..10 (x bits 5..3) ----
    #pragma unroll
    for (int it = 0; it < 2; ++it){
      int s4 = t + NT * it;
      int base = (s4 & 7) | (((s4 >> 3) & 7) << 8) | (((s4 >> 6) & 3) << 6)
               | (((s4 >> 8) & 7) << 11);
      #pragma unroll
      for (int j = 0; j < 8; ++j) a[j] = S[POS(base | (j << 3))];
      #pragma unroll
      for (int q = 0; q < 3; ++q){
        float c = csT[2*(8+q)], s = csT[2*(8+q)+1];
        int m = 4 >> q;
        #pragma unroll
        for (int j = 0; j < 8; ++j){
          if (j & m) continue;
          rot2(a[j], a[j | m], c, s);
        }
      }
      #pragma unroll
      for (int j = 0; j < 8; ++j) S[POS(base | (j << 3))] = a[j];
    }
    __syncthreads();

    // ---- P4: RY qubits 11..13 (x bits 2..0) + RZ2 ----
    #pragma unroll
    for (int it = 0; it < 2; ++it){
      int s4 = t + NT * it;
      int base = ((s4 & 63) << 5) | (((s4 >> 6) & 3) << 3) | (((s4 >> 8) & 7) << 11);
      #pragma unroll
      for (int j = 0; j < 8; ++j) a[j] = S[POS(base | j)];
      #pragma unroll
      for (int q = 0; q < 3; ++q){
        float c = csT[2*(11+q)], s = csT[2*(11+q)+1];
        int m = 4 >> q;
        #pragma unroll
        for (int j = 0; j < 8; ++j){
          if (j & m) continue;
          rot2(a[j], a[j | m], c, s);
        }
      }
      #pragma unroll
      for (int j = 0; j < 8; ++j){
        int x = base | j;
        a[j] = cmulph(a[j], ph2H[x >> 7], ph2L[x & 127]);
      }
      #pragma unroll
      for (int j = 0; j < 8; ++j) S[POS(base | j)] = a[j];
    }
    __syncthreads();
  }

  // ---- measurement (final CNOT ring still pending -> gather via src) ----
  float z0=0.f, z1=0.f, x0s=0.f, x1s=0.f, y0s=0.f;
  {
    int sl = srcL[t & 127];
    #pragma unroll
    for (int j = 0; j < 16; ++j)
      a[j] = S[POS(srcH[(t >> 7) + 8*j] ^ sl)];

    #pragma unroll
    for (int j = 0; j < 16; ++j){
      float pw = a[j].x*a[j].x + a[j].y*a[j].y;
      z0 += (j & 8) ? -pw : pw;     // qubit0 = x bit13 = j bit3
      z1 += (j & 4) ? -pw : pw;     // qubit1 = x bit12 = j bit2
    }
    #pragma unroll
    for (int j = 0; j < 8; ++j){
      float2 p0 = a[j], p1 = a[j+8];
      x0s += 2.f*(p0.x*p1.x + p0.y*p1.y);
      y0s += 2.f*(p0.x*p1.y - p0.y*p1.x);
    }
    #pragma unroll
    for (int j = 0; j < 16; ++j){
      if (j & 4) continue;
      float2 p0 = a[j], p1 = a[j|4];
      x1s += 2.f*(p0.x*p1.x + p0.y*p1.y);
    }
  }
  #pragma unroll
  for (int o = 32; o >= 1; o >>= 1){
    z0  += __shfl_down(z0,  o, 64);
    z1  += __shfl_down(z1,  o, 64);
    x0s += __shfl_down(x0s, o, 64);
    x1s += __shfl_down(x1s, o, 64);
    y0s += __shfl_down(y0s, o, 64);
  }
  int wid = t >> 6, lane = t & 63;
  if (lane == 0){
    red[wid*5+0]=z0; red[wid*5+1]=z1; red[wid*5+2]=x0s; red[wid*5+3]=x1s; red[wid*5+4]=y0s;
  }
  __syncthreads();
  if (t < 5){
    float sum = 0.f;
    #pragma unroll
    for (int w = 0; w < 16; ++w) sum += red[w*5 + t];
    out[1 + b*5 + t] = sum;
  }
}

__global__ __launch_bounds__(512)
void qnn_loss(const int* __restrict__ y, float* __restrict__ out)
{
  __shared__ float red[8];
  int t = threadIdx.x;   // one thread per batch element
  const float* o = out + 1 + t*5;
  float o0=o[0], o1=o[1], o2=o[2], o3=o[3], o4=o[4];
  float m = fmaxf(fmaxf(fmaxf(o0,o1), fmaxf(o2,o3)), o4);
  float sum = expf(o0-m)+expf(o1-m)+expf(o2-m)+expf(o3-m)+expf(o4-m);
  float lse = m + logf(sum);
  int yi = y[t]; yi = yi < 0 ? 0 : (yi > 4 ? 4 : yi);
  float lb = lse - o[yi];

  #pragma unroll
  for (int ofs = 32; ofs >= 1; ofs >>= 1) lb += __shfl_down(lb, ofs, 64);
  if ((t & 63) == 0) red[t >> 6] = lb;
  __syncthreads();
  if (t == 0){
    float s = 0.f;
    #pragma unroll
    for (int w = 0; w < 8; ++w) s += red[w];
    out[0] = s / (float)BATCH;
  }
}

extern "C" void kernel_launch(void* const* d_in, const int* in_sizes, int n_in,
                              void* d_out, int out_size, void* d_ws, size_t ws_size,
                              hipStream_t stream)
{
  const void* z     = d_in[0];            // bf16 (re,im) pairs OR f32 real (sniffed)
  const void* theta = d_in[1];            // bf16 or f32 (sniffed)
  const int*  y     = (const int*)d_in[2];
  float*      out   = (float*)d_out;

  qnn_circuit<<<BATCH, NT, 0, stream>>>(z, theta, out);
  qnn_loss<<<1, 512, 0, stream>>>(y, out);
}

// Round 6
// 473.142 us; speedup vs baseline: 1.3166x; 1.3162x over previous
//
#include <hip/hip_runtime.h>
#include <hip/hip_bf16.h>

#define NQ     14
#define DIM    16384
#define NLAYER 16
#define BATCH  512
#define NT     1024

// bijective LDS swizzle: XOR bits 5..9 into bits 0..4
__device__ __forceinline__ int POS(int x){ return x ^ ((x >> 5) & 31); }

__device__ __forceinline__ float bf2f(unsigned int u16){
  union { unsigned int i; float f; } v; v.i = u16 << 16; return v.f;
}

__device__ __forceinline__ float thv(const void* th, int i, bool b16){
  return b16 ? bf2f(((const unsigned short*)th)[i]) : ((const float*)th)[i];
}

// Composed CNOT-ring source map (GF(2)-linear): psi_out[x] = psi_in[srcF(x)]
__device__ int srcF(int x){
  int v = x;
  #pragma unroll
  for (int k = 13; k >= 0; --k){
    int tb = 13 - ((k + 1) % 14);
    v ^= ((v >> (13 - k)) & 1) << tb;
  }
  return v;
}

__device__ __forceinline__ void rot2(float2& a0, float2& a1, float c, float s){
  float2 t0 = a0, t1 = a1;
  a0 = make_float2(c*t0.x - s*t1.x, c*t0.y - s*t1.y);
  a1 = make_float2(s*t0.x + c*t1.x, s*t0.y + c*t1.y);
}

__device__ __forceinline__ float2 cmulph(float2 a, float2 ch, float2 cl){
  float cc = ch.x*cl.x - ch.y*cl.y;
  float ss = ch.x*cl.y + ch.y*cl.x;
  return make_float2(a.x*cc - a.y*ss, a.x*ss + a.y*cc);
}

// Phase ladder (register-pressure-minimized):
//   P1 : gather(CNOT^-1) + RZ0 + RY q0-3  (x bits 13..10)  a[16] (forced by gather)
//   P2': RY q4-6  (x bits 9..7)                            a[8]
//   P3': RY q7-9  (x bits 6..4)                            a[8]
//   P4': RY q10-11 (x bits 3..2)                           a[4]
//   P5': RY q12-13 (x bits 1..0) + RZ2                     a[4]
// Each mapping chosen so bank bits have rank 5 over the 6 lane bits (2-way min).
__global__ __launch_bounds__(NT) __attribute__((amdgpu_waves_per_eu(4, 4)))
void qnn_circuit(const void* __restrict__ zraw,
                 const void* __restrict__ theta,
                 float* __restrict__ out)
{
  __shared__ float2 S[DIM];
  __shared__ float2 ph0H[128], ph0L[128], ph2H[128], ph2L[128];
  __shared__ float  csT[28];
  __shared__ int    srcH[128], srcL[128];
  __shared__ float  red[16*5];

  const int t = threadIdx.x;
  const int b = blockIdx.x;

  // ---- sniff theta dtype: bf16 vs float32 ----
  int pred = 0;
  if (t < 336){
    unsigned int w  = ((const unsigned int*)theta)[t];
    unsigned int lo = w & 0xffffu;
    unsigned int e  = (lo >> 7) & 0xffu;
    pred = (e >= 100 && e <= 140) || (lo == 0);
  }
  const bool th_b16 = (__syncthreads_count(pred) > 250);

  // ---- sniff z format: bf16 (re,im) pairs vs float32 real-only ----
  pred = 0;
  if (t < 256){
    unsigned int w  = ((const unsigned int*)zraw)[t];
    unsigned int lo = w & 0xffffu;
    unsigned int e  = (lo >> 7) & 0xffu;
    pred = (e >= 88 && e <= 140) || (lo == 0);
  }
  const bool z_b16 = (__syncthreads_count(pred) > 160);

  if (t < 128){ srcH[t] = srcF(t << 7); srcL[t] = srcF(t); }

  // ---- load z -> LDS (swizzled) ----
  if (z_b16){
    const uint4* zb = (const uint4*)((const unsigned short*)zraw + (size_t)b * (DIM * 2));
    #pragma unroll 1
    for (int jj = 0; jj < 4; ++jj){
      int x4 = t + NT * jj;
      uint4 w = zb[x4];
      int xb = x4 * 4;
      S[POS(xb+0)] = make_float2(bf2f(w.x & 0xffffu), bf2f(w.x >> 16));
      S[POS(xb+1)] = make_float2(bf2f(w.y & 0xffffu), bf2f(w.y >> 16));
      S[POS(xb+2)] = make_float2(bf2f(w.z & 0xffffu), bf2f(w.z >> 16));
      S[POS(xb+3)] = make_float2(bf2f(w.w & 0xffffu), bf2f(w.w >> 16));
    }
  } else {
    const float4* zf = (const float4*)((const float*)zraw + (size_t)b * DIM);
    #pragma unroll 1
    for (int jj = 0; jj < 4; ++jj){
      int x4 = t + NT * jj;
      float4 w = zf[x4];
      int xb = x4 * 4;
      S[POS(xb+0)] = make_float2(w.x, 0.f);
      S[POS(xb+1)] = make_float2(w.y, 0.f);
      S[POS(xb+2)] = make_float2(w.z, 0.f);
      S[POS(xb+3)] = make_float2(w.w, 0.f);
    }
  }
  __syncthreads();

  for (int l = 0; l < NLAYER; ++l){
    const int thb = l * 42;

    // ---- prep RZ phase tables + RY angles (runs before the gather-sync) ----
    if (t < 512){
      int grp = t >> 7, idx = t & 127;
      int tz = thb + ((grp >= 2) ? 28 : 0);
      float ph = 0.f;
      if ((grp & 1) == 0){
        #pragma unroll
        for (int w = 0; w < 7; ++w)
          ph += (((idx >> (6 - w)) & 1) ? 0.5f : -0.5f) * thv(theta, tz + w, th_b16);
      } else {
        #pragma unroll
        for (int w = 7; w < 14; ++w)
          ph += (((idx >> (13 - w)) & 1) ? 0.5f : -0.5f) * thv(theta, tz + w, th_b16);
      }
      float sn, cs; sincosf(ph, &sn, &cs);
      float2 v = make_float2(cs, sn);
      if      (grp == 0) ph0H[idx] = v;
      else if (grp == 1) ph0L[idx] = v;
      else if (grp == 2) ph2H[idx] = v;
      else               ph2L[idx] = v;
    } else if (t < 512 + 14){
      int q = t - 512;
      float sn, cs; sincosf(0.5f * thv(theta, thb + 14 + q, th_b16), &sn, &cs);
      csT[2*q] = cs; csT[2*q+1] = sn;
    }

    // ---- P1: gather + RZ0 + RY q0-3 (x = t + 1024*j, j = bits 13..10) ----
    {
      float2 g[16];
      if (l == 0){
        #pragma unroll
        for (int j = 0; j < 16; ++j) g[j] = S[POS(t + NT*j)];
      } else {
        int sl = srcL[t & 127];
        #pragma unroll
        for (int j = 0; j < 16; ++j)
          g[j] = S[POS(srcH[(t >> 7) + 8*j] ^ sl)];
      }
      __syncthreads();   // all gathers done; tables visible

      {
        float2 cl = ph0L[t & 127];
        #pragma unroll
        for (int j = 0; j < 16; ++j)
          g[j] = cmulph(g[j], ph0H[(t >> 7) + 8*j], cl);
      }
      #pragma unroll
      for (int q = 0; q < 4; ++q){
        float c = csT[2*q], sn = csT[2*q+1];
        int m = 8 >> q;
        #pragma unroll
        for (int j = 0; j < 16; ++j){
          if (j & m) continue;
          rot2(g[j], g[j | m], c, sn);
        }
      }
      #pragma unroll
      for (int j = 0; j < 16; ++j) S[POS(t + NT*j)] = g[j];
    }
    __syncthreads();

    // ---- P2': RY q4-6 (x bits 9..7) ----
    #pragma unroll 1
    for (int it = 0; it < 2; ++it){
      int s = t + NT * it;
      int base = ((s >> 7) << 10) | (s & 127);
      float2 h[8];
      #pragma unroll
      for (int j = 0; j < 8; ++j) h[j] = S[POS(base | (j << 7))];
      #pragma unroll
      for (int q = 0; q < 3; ++q){
        float c = csT[2*(4+q)], sn = csT[2*(4+q)+1];
        int m = 4 >> q;
        #pragma unroll
        for (int j = 0; j < 8; ++j){
          if (j & m) continue;
          rot2(h[j], h[j | m], c, sn);
        }
      }
      #pragma unroll
      for (int j = 0; j < 8; ++j) S[POS(base | (j << 7))] = h[j];
    }
    __syncthreads();

    // ---- P3': RY q7-9 (x bits 6..4) ----
    #pragma unroll 1
    for (int it = 0; it < 2; ++it){
      int s = t + NT * it;
      int base = ((s >> 7) << 10) | (((s >> 5) & 1) << 9) | (((s >> 4) & 1) << 8)
               | (((s >> 6) & 1) << 7) | (s & 15);
      float2 h[8];
      #pragma unroll
      for (int j = 0; j < 8; ++j) h[j] = S[POS(base | (j << 4))];
      #pragma unroll
      for (int q = 0; q < 3; ++q){
        float c = csT[2*(7+q)], sn = csT[2*(7+q)+1];
        int m = 4 >> q;
        #pragma unroll
        for (int j = 0; j < 8; ++j){
          if (j & m) continue;
          rot2(h[j], h[j | m], c, sn);
        }
      }
      #pragma unroll
      for (int j = 0; j < 8; ++j) S[POS(base | (j << 4))] = h[j];
    }
    __syncthreads();

    // ---- P4': RY q10-11 (x bits 3..2) ----
    #pragma unroll 1
    for (int it = 0; it < 4; ++it){
      int s = t + NT * it;
      int base = ((s >> 8) << 10) | (((s >> 4) & 1) << 9) | (((s >> 3) & 1) << 8)
               | (((s >> 2) & 1) << 7) | (((s >> 6) & 1) << 6) | (((s >> 5) & 1) << 5)
               | (((s >> 7) & 1) << 4) | (s & 3);
      float2 h[4];
      #pragma unroll
      for (int j = 0; j < 4; ++j) h[j] = S[POS(base | (j << 2))];
      #pragma unroll
      for (int q = 0; q < 2; ++q){
        float c = csT[2*(10+q)], sn = csT[2*(10+q)+1];
        int m = 2 >> q;
        #pragma unroll
        for (int j = 0; j < 4; ++j){
          if (j & m) continue;
          rot2(h[j], h[j | m], c, sn);
        }
      }
      #pragma unroll
      for (int j = 0; j < 4; ++j) S[POS(base | (j << 2))] = h[j];
    }
    __syncthreads();

    // ---- P5': RY q12-13 (x bits 1..0) + RZ2 ----
    #pragma unroll 1
    for (int it = 0; it < 4; ++it){
      int s = t + NT * it;
      int base = ((s >> 8) << 10) | ((s & 31) << 5) | (((s >> 7) & 1) << 4)
               | (((s >> 6) & 1) << 3) | (((s >> 5) & 1) << 2);
      float2 h[4];
      #pragma unroll
      for (int j = 0; j < 4; ++j) h[j] = S[POS(base | j)];
      #pragma unroll
      for (int q = 0; q < 2; ++q){
        float c = csT[2*(12+q)], sn = csT[2*(12+q)+1];
        int m = 2 >> q;
        #pragma unroll
        for (int j = 0; j < 4; ++j){
          if (j & m) continue;
          rot2(h[j], h[j | m], c, sn);
        }
      }
      #pragma unroll
      for (int j = 0; j < 4; ++j){
        int x = base | j;
        h[j] = cmulph(h[j], ph2H[x >> 7], ph2L[x & 127]);
      }
      #pragma unroll
      for (int j = 0; j < 4; ++j) S[POS(base | j)] = h[j];
    }
    __syncthreads();
  }

  // ---- measurement (final CNOT ring pending -> gather via src) ----
  float z0=0.f, z1=0.f, x0s=0.f, x1s=0.f, y0s=0.f;
  {
    float2 g[16];
    int sl = srcL[t & 127];
    #pragma unroll
    for (int j = 0; j < 16; ++j)
      g[j] = S[POS(srcH[(t >> 7) + 8*j] ^ sl)];

    #pragma unroll
    for (int j = 0; j < 16; ++j){
      float pw = g[j].x*g[j].x + g[j].y*g[j].y;
      z0 += (j & 8) ? -pw : pw;
      z1 += (j & 4) ? -pw : pw;
    }
    #pragma unroll
    for (int j = 0; j < 8; ++j){
      float2 p0 = g[j], p1 = g[j+8];
      x0s += 2.f*(p0.x*p1.x + p0.y*p1.y);
      y0s += 2.f*(p0.x*p1.y - p0.y*p1.x);
    }
    #pragma unroll
    for (int j = 0; j < 16; ++j){
      if (j & 4) continue;
      float2 p0 = g[j], p1 = g[j|4];
      x1s += 2.f*(p0.x*p1.x + p0.y*p1.y);
    }
  }
  #pragma unroll
  for (int o = 32; o >= 1; o >>= 1){
    z0  += __shfl_down(z0,  o, 64);
    z1  += __shfl_down(z1,  o, 64);
    x0s += __shfl_down(x0s, o, 64);
    x1s += __shfl_down(x1s, o, 64);
    y0s += __shfl_down(y0s, o, 64);
  }
  int wid = t >> 6, lane = t & 63;
  if (lane == 0){
    red[wid*5+0]=z0; red[wid*5+1]=z1; red[wid*5+2]=x0s; red[wid*5+3]=x1s; red[wid*5+4]=y0s;
  }
  __syncthreads();
  if (t < 5){
    float sum = 0.f;
    #pragma unroll
    for (int w = 0; w < 16; ++w) sum += red[w*5 + t];
    out[1 + b*5 + t] = sum;
  }
}

__global__ __launch_bounds__(512)
void qnn_loss(const int* __restrict__ y, float* __restrict__ out)
{
  __shared__ float red[8];
  int t = threadIdx.x;
  const float* o = out + 1 + t*5;
  float o0=o[0], o1=o[1], o2=o[2], o3=o[3], o4=o[4];
  float m = fmaxf(fmaxf(fmaxf(o0,o1), fmaxf(o2,o3)), o4);
  float sum = expf(o0-m)+expf(o1-m)+expf(o2-m)+expf(o3-m)+expf(o4-m);
  float lse = m + logf(sum);
  int yi = y[t]; yi = yi < 0 ? 0 : (yi > 4 ? 4 : yi);
  float lb = lse - o[yi];

  #pragma unroll
  for (int ofs = 32; ofs >= 1; ofs >>= 1) lb += __shfl_down(lb, ofs, 64);
  if ((t & 63) == 0) red[t >> 6] = lb;
  __syncthreads();
  if (t == 0){
    float s = 0.f;
    #pragma unroll
    for (int w = 0; w < 8; ++w) s += red[w];
    out[0] = s / (float)BATCH;
  }
}

extern "C" void kernel_launch(void* const* d_in, const int* in_sizes, int n_in,
                              void* d_out, int out_size, void* d_ws, size_t ws_size,
                              hipStream_t stream)
{
  const void* z     = d_in[0];
  const void* theta = d_in[1];
  const int*  y     = (const int*)d_in[2];
  float*      out   = (float*)d_out;

  qnn_circuit<<<BATCH, NT, 0, stream>>>(z, theta, out);
  qnn_loss<<<1, 512, 0, stream>>>(y, out);
}

// Round 7
// 305.392 us; speedup vs baseline: 2.0398x; 1.5493x over previous
//
#include <hip/hip_runtime.h>
#include <hip/hip_bf16.h>

#define NQ     14
#define DIM    16384
#define NLAYER 16
#define BATCH  512
#define NT     1024

typedef float v2f __attribute__((ext_vector_type(2)));

// bijective LDS swizzle (XOR bits 5..9 into 0..4), in BYTE units (float2=8B).
// XOR-linear: POSB(a^b) = POSB(a)^POSB(b)  -> 1-xor addressing everywhere.
__device__ __forceinline__ constexpr int POSB(int x){ return (x ^ ((x >> 5) & 31)) << 3; }

__device__ __forceinline__ float bf2f(unsigned int u16){
  union { unsigned int i; float f; } v; v.i = u16 << 16; return v.f;
}

__device__ __forceinline__ float thv(const void* th, int i, bool b16){
  return b16 ? bf2f(((const unsigned short*)th)[i]) : ((const float*)th)[i];
}

// Composed CNOT-ring source map (GF(2)-linear): psi_out[x] = psi_in[srcF(x)]
__device__ int srcF(int x){
  int v = x;
  #pragma unroll
  for (int k = 13; k >= 0; --k){
    int tb = 13 - ((k + 1) % 14);
    v ^= ((v >> (13 - k)) & 1) << tb;
  }
  return v;
}

// complex multiply: packed (v_pk_mul/v_pk_fma + op_sel)
__device__ __forceinline__ v2f cmul(v2f a, v2f b){
  v2f as = a.yx;
  v2f br = (v2f){ b.x,  b.x};
  v2f bi = (v2f){-b.y,  b.y};
  return a * br + as * bi;
}

// RY rotation on a pair: 4 packed instrs
__device__ __forceinline__ void rot2(v2f& a0, v2f& a1, float c, float s){
  v2f c2 = (v2f){c, c}, s2 = (v2f){s, s};
  v2f t0 = a0;
  a0 = a0 * c2 - a1 * s2;
  a1 = t0 * s2 + a1 * c2;
}

// Phase ladder:
//   P1 : gather(CNOT^-1) + RZ0 + RY q0-3  (x bits 13..10)  g[16]
//   P2': RY q4-6  (x bits 9..7)                            h[8]
//   P3': RY q7-9  (x bits 6..4)                            h[8]
//   P4': RY q10-11 (x bits 3..2)                           h[4]
//   P5': RY q12-13 (x bits 1..0) + RZ2                     h[4]
__global__ __launch_bounds__(NT) __attribute__((amdgpu_waves_per_eu(4, 4)))
void qnn_circuit(const void* __restrict__ zraw,
                 const void* __restrict__ theta,
                 float* __restrict__ out)
{
  __shared__ v2f   S[DIM];
  __shared__ v2f   ph0H[128], ph0L[128], ph2H[128], ph2L[128];
  __shared__ float csT[28];
  __shared__ int   sHB[128], sLB[128];   // pre-swizzled BYTE offsets of srcF
  __shared__ float red[16*5];

  char* Sb = (char*)S;
  const int t = threadIdx.x;
  const int b = blockIdx.x;

  // ---- sniff theta dtype: bf16 vs float32 ----
  int pred = 0;
  if (t < 336){
    unsigned int w  = ((const unsigned int*)theta)[t];
    unsigned int lo = w & 0xffffu;
    unsigned int e  = (lo >> 7) & 0xffu;
    pred = (e >= 100 && e <= 140) || (lo == 0);
  }
  const bool th_b16 = (__syncthreads_count(pred) > 250);

  // ---- sniff z format: bf16 (re,im) pairs vs float32 real-only ----
  pred = 0;
  if (t < 256){
    unsigned int w  = ((const unsigned int*)zraw)[t];
    unsigned int lo = w & 0xffffu;
    unsigned int e  = (lo >> 7) & 0xffu;
    pred = (e >= 88 && e <= 140) || (lo == 0);
  }
  const bool z_b16 = (__syncthreads_count(pred) > 160);

  if (t < 128){ sHB[t] = POSB(srcF(t << 7)); sLB[t] = POSB(srcF(t)); }

  // ---- load z -> LDS (swizzled) ----
  if (z_b16){
    const uint4* zb = (const uint4*)((const unsigned short*)zraw + (size_t)b * (DIM * 2));
    #pragma unroll 1
    for (int jj = 0; jj < 4; ++jj){
      int x4 = t + NT * jj;
      uint4 w = zb[x4];
      int xb = x4 * 4;
      *(v2f*)(Sb + POSB(xb+0)) = (v2f){bf2f(w.x & 0xffffu), bf2f(w.x >> 16)};
      *(v2f*)(Sb + POSB(xb+1)) = (v2f){bf2f(w.y & 0xffffu), bf2f(w.y >> 16)};
      *(v2f*)(Sb + POSB(xb+2)) = (v2f){bf2f(w.z & 0xffffu), bf2f(w.z >> 16)};
      *(v2f*)(Sb + POSB(xb+3)) = (v2f){bf2f(w.w & 0xffffu), bf2f(w.w >> 16)};
    }
  } else {
    const float4* zf = (const float4*)((const float*)zraw + (size_t)b * DIM);
    #pragma unroll 1
    for (int jj = 0; jj < 4; ++jj){
      int x4 = t + NT * jj;
      float4 w = zf[x4];
      int xb = x4 * 4;
      *(v2f*)(Sb + POSB(xb+0)) = (v2f){w.x, 0.f};
      *(v2f*)(Sb + POSB(xb+1)) = (v2f){w.y, 0.f};
      *(v2f*)(Sb + POSB(xb+2)) = (v2f){w.z, 0.f};
      *(v2f*)(Sb + POSB(xb+3)) = (v2f){w.w, 0.f};
    }
  }
  __syncthreads();

  const int pwb = POSB(t);        // P1 write base (byte, swizzled) — thread-invariant
  const int hb  = t >> 7;         // P1 hi-table base index
  int slB;                        // gather lo-offset — set after sLB is visible
  slB = sLB[t & 127];             // (sLB written pre-z-load barrier by t<128) — visible after __syncthreads above

  for (int l = 0; l < NLAYER; ++l){
    const int thb = l * 42;

    // ---- prep RZ phase tables + RY angles (overlaps with P1 gather) ----
    if (t < 512){
      int grp = t >> 7, idx = t & 127;
      int tz = thb + ((grp >= 2) ? 28 : 0);
      float ph = 0.f;
      if ((grp & 1) == 0){
        #pragma unroll
        for (int w = 0; w < 7; ++w)
          ph += (((idx >> (6 - w)) & 1) ? 0.5f : -0.5f) * thv(theta, tz + w, th_b16);
      } else {
        #pragma unroll
        for (int w = 7; w < 14; ++w)
          ph += (((idx >> (13 - w)) & 1) ? 0.5f : -0.5f) * thv(theta, tz + w, th_b16);
      }
      float sn, cs; sincosf(ph, &sn, &cs);
      v2f v = (v2f){cs, sn};
      if      (grp == 0) ph0H[idx] = v;
      else if (grp == 1) ph0L[idx] = v;
      else if (grp == 2) ph2H[idx] = v;
      else               ph2L[idx] = v;
    } else if (t < 512 + 14){
      int q = t - 512;
      float sn, cs; sincosf(0.5f * thv(theta, thb + 14 + q, th_b16), &sn, &cs);
      csT[2*q] = cs; csT[2*q+1] = sn;
    }

    // ---- P1: gather + RZ0 + RY q0-3 (x = t | (j<<10)) ----
    {
      v2f g[16];
      if (l == 0){
        #pragma unroll
        for (int j = 0; j < 16; ++j) g[j] = *(v2f*)(Sb + (pwb ^ (j << 13)));
      } else {
        #pragma unroll
        for (int j = 0; j < 16; ++j)
          g[j] = *(v2f*)(Sb + (sHB[hb + 8*j] ^ slB));
      }
      __syncthreads();   // all gathers done; this layer's tables visible

      {
        v2f cl = ph0L[t & 127];
        #pragma unroll
        for (int j = 0; j < 16; ++j)
          g[j] = cmul(g[j], cmul(ph0H[hb + 8*j], cl));
      }
      #pragma unroll
      for (int q = 0; q < 4; ++q){
        float c = csT[2*q], sn = csT[2*q+1];
        int m = 8 >> q;
        #pragma unroll
        for (int j = 0; j < 16; ++j){
          if (j & m) continue;
          rot2(g[j], g[j | m], c, sn);
        }
      }
      #pragma unroll
      for (int j = 0; j < 16; ++j) *(v2f*)(Sb + (pwb ^ (j << 13))) = g[j];
    }
    __syncthreads();

    // ---- P2': RY q4-6 (x bits 9..7) ----
    #pragma unroll 1
    for (int it = 0; it < 2; ++it){
      int s = t + NT * it;
      int pb = POSB(((s >> 7) << 10) | (s & 127));
      v2f h[8];
      #pragma unroll
      for (int j = 0; j < 8; ++j) h[j] = *(v2f*)(Sb + (pb ^ POSB(j << 7)));
      #pragma unroll
      for (int q = 0; q < 3; ++q){
        float c = csT[2*(4+q)], sn = csT[2*(4+q)+1];
        int m = 4 >> q;
        #pragma unroll
        for (int j = 0; j < 8; ++j){
          if (j & m) continue;
          rot2(h[j], h[j | m], c, sn);
        }
      }
      #pragma unroll
      for (int j = 0; j < 8; ++j) *(v2f*)(Sb + (pb ^ POSB(j << 7))) = h[j];
    }
    __syncthreads();

    // ---- P3': RY q7-9 (x bits 6..4) ----
    #pragma unroll 1
    for (int it = 0; it < 2; ++it){
      int s = t + NT * it;
      int pb = POSB(((s >> 7) << 10) | (((s >> 5) & 1) << 9) | (((s >> 4) & 1) << 8)
                  | (((s >> 6) & 1) << 7) | (s & 15));
      v2f h[8];
      #pragma unroll
      for (int j = 0; j < 8; ++j) h[j] = *(v2f*)(Sb + (pb ^ POSB(j << 4)));
      #pragma unroll
      for (int q = 0; q < 3; ++q){
        float c = csT[2*(7+q)], sn = csT[2*(7+q)+1];
        int m = 4 >> q;
        #pragma unroll
        for (int j = 0; j < 8; ++j){
          if (j & m) continue;
          rot2(h[j], h[j | m], c, sn);
        }
      }
      #pragma unroll
      for (int j = 0; j < 8; ++j) *(v2f*)(Sb + (pb ^ POSB(j << 4))) = h[j];
    }
    __syncthreads();

    // ---- P4': RY q10-11 (x bits 3..2) ----
    #pragma unroll 1
    for (int it = 0; it < 4; ++it){
      int s = t + NT * it;
      int pb = POSB(((s >> 8) << 10) | (((s >> 4) & 1) << 9) | (((s >> 3) & 1) << 8)
                  | (((s >> 2) & 1) << 7) | (((s >> 6) & 1) << 6) | (((s >> 5) & 1) << 5)
                  | (((s >> 7) & 1) << 4) | (s & 3));
      v2f h[4];
      #pragma unroll
      for (int j = 0; j < 4; ++j) h[j] = *(v2f*)(Sb + (pb ^ POSB(j << 2)));
      #pragma unroll
      for (int q = 0; q < 2; ++q){
        float c = csT[2*(10+q)], sn = csT[2*(10+q)+1];
        int m = 2 >> q;
        #pragma unroll
        for (int j = 0; j < 4; ++j){
          if (j & m) continue;
          rot2(h[j], h[j | m], c, sn);
        }
      }
      #pragma unroll
      for (int j = 0; j < 4; ++j) *(v2f*)(Sb + (pb ^ POSB(j << 2))) = h[j];
    }
    __syncthreads();

    // ---- P5': RY q12-13 (x bits 1..0) + RZ2 ----
    #pragma unroll 1
    for (int it = 0; it < 4; ++it){
      int s = t + NT * it;
      int x0 = ((s >> 8) << 10) | ((s & 31) << 5) | (((s >> 7) & 1) << 4)
             | (((s >> 6) & 1) << 3) | (((s >> 5) & 1) << 2);
      int pb = POSB(x0);
      v2f h[4];
      #pragma unroll
      for (int j = 0; j < 4; ++j) h[j] = *(v2f*)(Sb + (pb ^ (j << 3)));
      #pragma unroll
      for (int q = 0; q < 2; ++q){
        float c = csT[2*(12+q)], sn = csT[2*(12+q)+1];
        int m = 2 >> q;
        #pragma unroll
        for (int j = 0; j < 4; ++j){
          if (j & m) continue;
          rot2(h[j], h[j | m], c, sn);
        }
      }
      {
        v2f chh = ph2H[x0 >> 7];
        #pragma unroll
        for (int j = 0; j < 4; ++j)
          h[j] = cmul(h[j], cmul(chh, ph2L[(x0 | j) & 127]));
      }
      #pragma unroll
      for (int j = 0; j < 4; ++j) *(v2f*)(Sb + (pb ^ (j << 3))) = h[j];
    }
    __syncthreads();
  }

  // ---- measurement (final CNOT ring pending -> gather via src tables) ----
  float z0=0.f, z1=0.f, x0s=0.f, x1s=0.f, y0s=0.f;
  {
    v2f g[16];
    #pragma unroll
    for (int j = 0; j < 16; ++j)
      g[j] = *(v2f*)(Sb + (sHB[hb + 8*j] ^ slB));

    #pragma unroll
    for (int j = 0; j < 16; ++j){
      float pw = g[j].x*g[j].x + g[j].y*g[j].y;
      z0 += (j & 8) ? -pw : pw;     // qubit0 = x bit13 = j bit3
      z1 += (j & 4) ? -pw : pw;     // qubit1 = x bit12 = j bit2
    }
    #pragma unroll
    for (int j = 0; j < 8; ++j){
      v2f p0 = g[j], p1 = g[j+8];
      x0s += 2.f*(p0.x*p1.x + p0.y*p1.y);
      y0s += 2.f*(p0.x*p1.y - p0.y*p1.x);
    }
    #pragma unroll
    for (int j = 0; j < 16; ++j){
      if (j & 4) continue;
      v2f p0 = g[j], p1 = g[j|4];
      x1s += 2.f*(p0.x*p1.x + p0.y*p1.y);
    }
  }
  #pragma unroll
  for (int o = 32; o >= 1; o >>= 1){
    z0  += __shfl_down(z0,  o, 64);
    z1  += __shfl_down(z1,  o, 64);
    x0s += __shfl_down(x0s, o, 64);
    x1s += __shfl_down(x1s, o, 64);
    y0s += __shfl_down(y0s, o, 64);
  }
  int wid = t >> 6, lane = t & 63;
  if (lane == 0){
    red[wid*5+0]=z0; red[wid*5+1]=z1; red[wid*5+2]=x0s; red[wid*5+3]=x1s; red[wid*5+4]=y0s;
  }
  __syncthreads();
  if (t < 5){
    float sum = 0.f;
    #pragma unroll
    for (int w = 0; w < 16; ++w) sum += red[w*5 + t];
    out[1 + b*5 + t] = sum;
  }
}

__global__ __launch_bounds__(512)
void qnn_loss(const int* __restrict__ y, float* __restrict__ out)
{
  __shared__ float red[8];
  int t = threadIdx.x;
  const float* o = out + 1 + t*5;
  float o0=o[0], o1=o[1], o2=o[2], o3=o[3], o4=o[4];
  float m = fmaxf(fmaxf(fmaxf(o0,o1), fmaxf(o2,o3)), o4);
  float sum = expf(o0-m)+expf(o1-m)+expf(o2-m)+expf(o3-m)+expf(o4-m);
  float lse = m + logf(sum);
  int yi = y[t]; yi = yi < 0 ? 0 : (yi > 4 ? 4 : yi);
  float lb = lse - o[yi];

  #pragma unroll
  for (int ofs = 32; ofs >= 1; ofs >>= 1) lb += __shfl_down(lb, ofs, 64);
  if ((t & 63) == 0) red[t >> 6] = lb;
  __syncthreads();
  if (t == 0){
    float s = 0.f;
    #pragma unroll
    for (int w = 0; w < 8; ++w) s += red[w];
    out[0] = s / (float)BATCH;
  }
}

extern "C" void kernel_launch(void* const* d_in, const int* in_sizes, int n_in,
                              void* d_out, int out_size, void* d_ws, size_t ws_size,
                              hipStream_t stream)
{
  const void* z     = d_in[0];
  const void* theta = d_in[1];
  const int*  y     = (const int*)d_in[2];
  float*      out   = (float*)d_out;

  qnn_circuit<<<BATCH, NT, 0, stream>>>(z, theta, out);
  qnn_loss<<<1, 512, 0, stream>>>(y, out);
}